// Round 6
// baseline (216.029 us; speedup 1.0000x reference)
//
#include <hip/hip_runtime.h>
#include <hip/hip_bf16.h>
#include <stdint.h>

#define NPTS 131072
#define DIM  512
#define KC   512
#define BM   64
#define NKT  16          // DIM / 32

typedef float f32x16 __attribute__((ext_vector_type(16)));
typedef float f32x4  __attribute__((ext_vector_type(4)));
typedef short bf16x8 __attribute__((ext_vector_type(8)));

__device__ __forceinline__ float sq4(f32x4 a) {
  return a.x*a.x + a.y*a.y + a.z*a.z + a.w*a.w;
}

// packed RNE fp32->bf16 (v_cvt_pk_bf16_f32 via HIP intrinsic)
__device__ __forceinline__ bf16x8 pack8c(f32x4 a, f32x4 b) {
  bf16x8 r;
  float v[8] = {a.x, a.y, a.z, a.w, b.x, b.y, b.z, b.w};
  #pragma unroll
  for (int i = 0; i < 4; ++i) {
    __hip_bfloat162 t = __float22bfloat162_rn(make_float2(v[2*i], v[2*i+1]));
    union { __hip_bfloat162 h; short s[2]; } u; u.h = t;
    r[2*i]   = u.s[0];
    r[2*i+1] = u.s[1];
  }
  return r;
}

// legacy scalar RNE (used in dec_pack where VALU cost is irrelevant)
__device__ __forceinline__ short f2bf(float f) {
  union { float f; unsigned u; } v; v.f = f;
  unsigned r = v.u + 0x7FFFu + ((v.u >> 16) & 1u);
  return (short)(r >> 16);
}
__device__ __forceinline__ bf16x8 pack8(f32x4 a, f32x4 b) {
  bf16x8 p;
  p[0] = f2bf(a.x); p[1] = f2bf(a.y); p[2] = f2bf(a.z); p[3] = f2bf(a.w);
  p[4] = f2bf(b.x); p[5] = f2bf(b.y); p[6] = f2bf(b.z); p[7] = f2bf(b.w);
  return p;
}

// ---------------------------------------------------------------------------
// Pre-kernel (unchanged from R5): clusters fp32 [512][512] -> bf16 packed in
// MFMA-fragment order: 16B slot = (((kt*2+s)*4 + wn)*4 + nt)*64 + h*32 + r,
// n = wn*128+nt*32+r, k = kt*32 + s*16 + h*8 + j. Main kernel loads fragments
// STRAIGHT TO REGISTERS (contiguous 1 KB per wave-instr, L2-resident 512 KB).
// Also c2[n] = ||c_n||^2 (fp32).
// ---------------------------------------------------------------------------
__global__ void dec_pack(const float* __restrict__ C, short* __restrict__ Bp,
                         float* __restrict__ c2) {
  const int n    = blockIdx.x;
  const int lane = threadIdx.x;
  const float* src = C + (size_t)n * DIM + lane * 8;
  f32x4 v0 = *(const f32x4*)src;
  f32x4 v1 = *(const f32x4*)(src + 4);
  float s = sq4(v0) + sq4(v1);
  #pragma unroll
  for (int m = 1; m < 64; m <<= 1) s += __shfl_xor(s, m, 64);
  if (lane == 0) c2[n] = s;
  const int kt = lane >> 2;
  const int st = (lane >> 1) & 1;
  const int hh = lane & 1;
  const int wn = n >> 7, nt = (n >> 5) & 3, r = n & 31;
  const size_t slot =
      (((size_t)(kt * 2 + st) * 4 + wn) * 4 + nt) * 64 + hh * 32 + r;
  *(bf16x8*)(Bp + slot * 8) = pack8(v0, v1);
}

// ---------------------------------------------------------------------------
// Main fused kernel — ZERO barriers in the K loop.
// 512 threads = 8 waves (wm = wave>>2, wn = wave&3); block 64 x 512.
// Wave tile 32x128, 8 x mfma_f32_32x32x16_bf16 per kt (BK=32).
//
// B: fragment loads straight from pre-packed Bp (global, L2-resident,
//    contiguous 16 B/lane per fragment — fully coalesced). No LDS. No sync.
// A: WAVE-PRIVATE LDS staging (same-wave DS ordering -> no barriers),
//    software-pipelined 2 deep in registers:
//      iter kt: issue A(kt+2) global loads -> regs | cvt+ds_write A(kt+1)
//               from regs loaded last iter | ds_read frag + MFMA on kt.
//    Lane role: rows (l>>2)+16j (j=0,1), k-chunk (l&3)*8 floats: 2 dwordx4
//    per (lane,j), 4 lanes cover a full 128B row-slice (coalesced).
//    LDS layout [t=(l&3)][row][16B]: frag read = base + l31*16 per t-region
//    (linear, conflict-free); write = 2 x b128 per lane.
// x2 in exact fp32, butterfly over the 4 k-chunk lanes, shfl redistribution.
// Epilogue: q = rcp(1+d2), row-sums, ONE __syncthreads, normalize, store.
// ---------------------------------------------------------------------------
__global__ __launch_bounds__(512, 2)
void dec_main(const float* __restrict__ X, const short* __restrict__ Bp,
              const float* __restrict__ c2g, float* __restrict__ out) {
  __shared__ short Apriv[8][2][1024];   // per-wave dbuf: [t0..3][32 rows][8]
  __shared__ float part[4][BM];
  __shared__ float rowinv[BM];

  const int tid  = threadIdx.x;
  const int lane = tid & 63;
  const int wave = tid >> 6;
  const int wm   = wave >> 2;   // 0..1 : row half
  const int wn   = wave & 3;    // 0..3 : column quarter
  const int l31  = lane & 31;
  const int h    = lane >> 5;
  const int row0 = blockIdx.x * BM;

  // A: lane covers rows wm*32 + (lane>>2) + 16j, floats (lane&3)*8 .. +7
  const float* aptr =
      X + (size_t)(row0 + wm * 32 + (lane >> 2)) * DIM + (lane & 3) * 8;
  // B fragment base (shorts): + kt*16384 + s*8192 + nt*512
  const short* bB = Bp + wn * 2048 + lane * 8;
  // A LDS write offset (shorts): t-region (lane&3), row (lane>>2) (+16j -> +128)
  const int awoff = (lane & 3) * 256 + (lane >> 2) * 8;

  f32x16 acc[4];
  #pragma unroll
  for (int nt = 0; nt < 4; ++nt) acc[nt] = (f32x16)0.f;
  float x2s[2] = {0.f, 0.f};

  // ---- prologue: write A(0), prime regs with A(1) ----
  {
    f32x4 a0[2][2];
    #pragma unroll
    for (int j = 0; j < 2; ++j) {
      a0[j][0] = *(const f32x4*)(aptr + j * 8192);
      a0[j][1] = *(const f32x4*)(aptr + j * 8192 + 4);
    }
    #pragma unroll
    for (int j = 0; j < 2; ++j) {
      x2s[j] += sq4(a0[j][0]) + sq4(a0[j][1]);
      *(bf16x8*)&Apriv[wave][0][awoff + j * 128] = pack8c(a0[j][0], a0[j][1]);
    }
  }
  f32x4 aC[2][2];
  #pragma unroll
  for (int j = 0; j < 2; ++j) {
    aC[j][0] = *(const f32x4*)(aptr + 32 + j * 8192);
    aC[j][1] = *(const f32x4*)(aptr + 32 + j * 8192 + 4);
  }

  // ---- barrier-free K loop ----
  #pragma unroll 2
  for (int kt = 0; kt < NKT; ++kt) {
    const int cur = kt & 1;

    // (1) issue A(kt+2) loads early (consumed 2 iterations later)
    f32x4 aN[2][2];
    if (kt + 2 < NKT) {
      #pragma unroll
      for (int j = 0; j < 2; ++j) {
        aN[j][0] = *(const f32x4*)(aptr + (kt + 2) * 32 + j * 8192);
        aN[j][1] = *(const f32x4*)(aptr + (kt + 2) * 32 + j * 8192 + 4);
      }
    }

    // (2) issue all 8 B-fragment loads for this kt (L2-resident)
    bf16x8 bq[2][4];
    #pragma unroll
    for (int s = 0; s < 2; ++s)
      #pragma unroll
      for (int nt = 0; nt < 4; ++nt)
        bq[s][nt] = *(const bf16x8*)(bB + kt * 16384 + s * 8192 + nt * 512);

    // (3) cvt + x2 + ds_write A(kt+1) from regs loaded last iteration
    if (kt + 1 < NKT) {
      #pragma unroll
      for (int j = 0; j < 2; ++j) {
        x2s[j] += sq4(aC[j][0]) + sq4(aC[j][1]);
        *(bf16x8*)&Apriv[wave][cur ^ 1][awoff + j * 128] =
            pack8c(aC[j][0], aC[j][1]);
      }
    }

    // (4) fragment reads (same-wave order after writes) + MFMA
    #pragma unroll
    for (int s = 0; s < 2; ++s) {
      bf16x8 af = *(const bf16x8*)&Apriv[wave][cur][(s * 2 + h) * 256 + l31 * 8];
      #pragma unroll
      for (int nt = 0; nt < 4; ++nt)
        acc[nt] = __builtin_amdgcn_mfma_f32_32x32x16_bf16(
            af, bq[s][nt], acc[nt], 0, 0, 0);
    }

    // (5) shift the A register pipeline
    #pragma unroll
    for (int j = 0; j < 2; ++j) {
      aC[j][0] = aN[j][0];
      aC[j][1] = aN[j][1];
    }
  }

  // ---- x2: reduce over the 4 k-chunk lanes; all lanes get both rows ----
  #pragma unroll
  for (int j = 0; j < 2; ++j) {
    x2s[j] += __shfl_xor(x2s[j], 1, 64);
    x2s[j] += __shfl_xor(x2s[j], 2, 64);
  }
  // x2 of local row rho (0..31) lives in lanes (rho&15)*4.. (j = rho>>4)

  float c2v[4];
  #pragma unroll
  for (int nt = 0; nt < 4; ++nt) c2v[nt] = c2g[wn * 128 + nt * 32 + l31];

  // ---- q = rcp(1+d2), per-row partial sums over this wave's 128 cols ----
  float srow[16];
  #pragma unroll
  for (int r = 0; r < 16; ++r) {
    const int mloc = (r & 3) + 8 * (r >> 2) + 4 * h;   // 0..31
    const float x2m = __shfl(x2s[mloc >> 4], (mloc & 15) * 4, 64);
    float s = 0.f;
    #pragma unroll
    for (int nt = 0; nt < 4; ++nt) {
      float d2 = fmaxf(x2m + c2v[nt] - 2.f * acc[nt][r], 0.f);
      float q = __builtin_amdgcn_rcpf(1.f + d2);
      acc[nt][r] = q;
      s += q;
    }
    #pragma unroll
    for (int msk = 1; msk < 32; msk <<= 1) s += __shfl_xor(s, msk, 64);
    srow[r] = s;
  }

  if (l31 == 0) {
    #pragma unroll
    for (int r = 0; r < 16; ++r)
      part[wn][wm * 32 + (r & 3) + 8 * (r >> 2) + 4 * h] = srow[r];
  }
  __syncthreads();
  if (tid < BM)
    rowinv[tid] = __builtin_amdgcn_rcpf(part[0][tid] + part[1][tid] +
                                        part[2][tid] + part[3][tid]);
  __syncthreads();

  // ---- normalize + coalesced stores ----
  #pragma unroll
  for (int r = 0; r < 16; ++r) {
    const int row = wm * 32 + (r & 3) + 8 * (r >> 2) + 4 * h;
    const float iv = rowinv[row];
    float* o = out + (size_t)(row0 + row) * KC + wn * 128 + l31;
    #pragma unroll
    for (int nt = 0; nt < 4; ++nt)
      o[nt * 32] = acc[nt][r] * iv;
  }
}

extern "C" void kernel_launch(void* const* d_in, const int* in_sizes, int n_in,
                              void* d_out, int out_size, void* d_ws, size_t ws_size,
                              hipStream_t stream) {
  const float* X = (const float*)d_in[0];   // inputs  [131072, 512] fp32
  const float* C = (const float*)d_in[1];   // clusters [512, 512] fp32
  float* out = (float*)d_out;               // [131072, 512] fp32

  short* Bp = (short*)d_ws;                                   // 512 KB packed bf16 clusters
  float* c2 = (float*)((char*)d_ws + (size_t)KC * DIM * 2);   // 2 KB cluster norms

  dec_pack<<<KC, 64, 0, stream>>>(C, Bp, c2);
  dec_main<<<NPTS / BM, 512, 0, stream>>>(X, Bp, c2, out);
}